// Round 4
// baseline (142.750 us; speedup 1.0000x reference)
//
#include <hip/hip_runtime.h>
#include <hip/hip_bf16.h>
#include <math.h>

#define D 128
#define INV_TAU 5.0f
#define BINS 512
#define BSTRIDE 520   // padded row stride (words) to break bank alignment
#define CCAP 384      // candidate capacity per row (expected ~50)

typedef short bf16x8 __attribute__((ext_vector_type(8)));
typedef float f32x4 __attribute__((ext_vector_type(4)));

// bin classifier — MUST be identical in pass1 and pass2 (inline fn => same code)
__device__ __forceinline__ int bin_of(float v) {
    float bf = fmaf(v, (float)(BINS / 2), (float)(BINS / 2));
    bf = fminf(fmaxf(bf, 0.0f), (float)(BINS - 1));
    return (int)bf;
}

// ---------- K1: pos[a] = b for each pair; zero the output scalar ----------
__global__ void scatter_pos(const int* __restrict__ pp, int* __restrict__ pos,
                            float* __restrict__ out, int K) {
    int k = blockIdx.x * blockDim.x + threadIdx.x;
    if (k == 0) *out = 0.0f;
    if (k < K) pos[pp[2 * k]] = pp[2 * k + 1];
}

// ---------- K2: prep — blocks [0,N): partner (inline) + hard_neg norm -> bf16;
//                      blocks [N,N+K): hard_pos norm -> fp32 ----------
__global__ void prep_kernel(const float* __restrict__ emb, const int* __restrict__ pos,
                            const int* __restrict__ pp, __hip_bfloat16* __restrict__ hnn,
                            float* __restrict__ hpn, int N) {
    int b = blockIdx.x, d = threadIdx.x;  // blockDim = 128
    __shared__ int sP;
    __shared__ float tmp[2];
    bool isHn = (b < N);
    if (isHn && d == 0) {
        int r = b, posr = pos[r];
        int jmax = -1;
        for (int j = N - 1; j >= 0; --j) {
            if (j != r && j != posr) { jmax = j; break; }
        }
        int imax = -1;
        for (int i = N - 1; i >= 0; --i) {
            if (i != r && pos[i] != r) { imax = i; break; }
        }
        long long rowm = (jmax >= 0) ? (long long)r * N + jmax : -1;
        long long colm = (imax >= 0) ? (long long)imax * N + r : -1;
        sP = (colm > rowm) ? (imax < 0 ? 0 : imax) : (jmax < 0 ? 0 : jmax);
    }
    __syncthreads();
    float h;
    int outrow;
    if (isHn) {
        int p = sP;
        h = 0.5f * (emb[b * D + d] + emb[p * D + d]);
        outrow = b;
    } else {
        int k = b - N;
        int a = pp[2 * k], bb = pp[2 * k + 1];
        h = 1.5f * emb[a * D + d] - 0.5f * emb[bb * D + d];
        outrow = a;
    }
    float ss = h * h;
#pragma unroll
    for (int off = 32; off > 0; off >>= 1) ss += __shfl_down(ss, off);
    if ((d & 63) == 0) tmp[d >> 6] = ss;
    __syncthreads();
    float inv = 1.0f / fmaxf(sqrtf(tmp[0] + tmp[1]), 1e-8f);
    if (isHn)
        hnn[outrow * D + d] = __float2bfloat16(h * inv);
    else
        hpn[outrow * D + d] = h * inv;
}

// ---------- K3: fused Gram (bf16 MFMA) + exact per-row rank-select + sum ----------
// Block = 1024 thr (16 waves) owns 16 rows; wave w owns cols [w*256, w*256+256).
// Sims are RECOMPUTED in pass 2 (deterministic => identical) instead of stored:
// frees ~64 VGPRs so both passes software-pipeline the load->MFMA->classify chain.
__global__ __launch_bounds__(1024, 4) void fused_gram_select(
    const __hip_bfloat16* __restrict__ hnn, const int* __restrict__ pos,
    const int* __restrict__ stage, float* __restrict__ s_out, int N, int q) {
    __shared__ unsigned hist[16 * BSTRIDE];  // 33.3 KB; reused as candidate floats
    __shared__ float rowSum[16];
    __shared__ float tVal_s[16];
    __shared__ int tBin_s[16], tRem_s[16], cCnt[16], pos_s[16];

    int tid = threadIdx.x;
    int wave = tid >> 6, lane = tid & 63;
    int quad = lane >> 4, l15 = lane & 15;
    int rowBase = blockIdx.x * 16;
    int st = stage[0];

    if (st) {
        for (int i = tid; i < 16 * BSTRIDE; i += 1024) hist[i] = 0;
    }
    if (tid < 16) {
        rowSum[tid] = 0.0f;
        cCnt[tid] = 0;
        tVal_s[tid] = -1e31f;
        pos_s[tid] = pos[rowBase + tid];
    }
    __syncthreads();

    const short* hs = (const short*)hnn;
    bf16x8 afrag[4];
#pragma unroll
    for (int kk = 0; kk < 4; ++kk)
        afrag[kk] = *(const bf16x8*)&hs[(rowBase + l15) * D + kk * 32 + quad * 8];

    const short* bp = hs + (size_t)(wave * 256 + l15) * D + quad * 8;

    // ---- pass 1: compute sims, histogram (only needed when stage!=0) ----
    if (st) {
        bf16x8 cur[4], nxt[4];
#pragma unroll
        for (int kk = 0; kk < 4; ++kk) cur[kk] = *(const bf16x8*)(bp + kk * 32);
#pragma unroll
        for (int t = 0; t < 16; ++t) {
            if (t < 15) {
                const short* np = bp + (t + 1) * 16 * D;
#pragma unroll
                for (int kk = 0; kk < 4; ++kk) nxt[kk] = *(const bf16x8*)(np + kk * 32);
            }
            f32x4 acc = {0.f, 0.f, 0.f, 0.f};
#pragma unroll
            for (int kk = 0; kk < 4; ++kk)
                acc = __builtin_amdgcn_mfma_f32_16x16x32_bf16(afrag[kk], cur[kk], acc, 0, 0, 0);
            int c = wave * 256 + t * 16 + l15;
#pragma unroll
            for (int rg = 0; rg < 4; ++rg) {
                int rloc = quad * 4 + rg;
                float v = acc[rg];
                bool masked = (c == rowBase + rloc) || (c == pos_s[rloc]);
                v = masked ? -1e30f : v;
                atomicAdd(&hist[rloc * BSTRIDE + bin_of(v)], 1u);
            }
#pragma unroll
            for (int kk = 0; kk < 4; ++kk) cur[kk] = nxt[kk];
        }
        __syncthreads();

        // ---- threshold: wave w locates target bin for row w ----
        {
            int rloc = wave;
            int base = lane * (BINS / 64);  // 8 bins per lane
            unsigned p = 0;
#pragma unroll
            for (int b = 0; b < BINS / 64; ++b) p += hist[rloc * BSTRIDE + base + b];
            unsigned incl = p;
#pragma unroll
            for (int off = 1; off < 64; off <<= 1) {
                unsigned nb = __shfl_up(incl, off);
                if (lane >= off) incl += nb;
            }
            unsigned excl = incl - p;
            unsigned uq = (unsigned)q;
            if (uq >= excl && uq < excl + p) {
                unsigned rem = uq - excl, acc2 = 0;
                int b = 0;
                for (; b < BINS / 64; ++b) {
                    unsigned h = hist[rloc * BSTRIDE + base + b];
                    if (acc2 + h > rem) break;
                    acc2 += h;
                }
                tBin_s[rloc] = base + b;
                tRem_s[rloc] = (int)(rem - acc2);
            }
        }
    } else {
        if (tid < 16) { tBin_s[tid] = -1; tRem_s[tid] = 0; }
    }
    __syncthreads();

    // ---- pass 2: recompute sims; sum exp of high bins, gather target-bin cands ----
    float* cand = (float*)hist;  // hist no longer needed
    {
        float partial[4] = {0.f, 0.f, 0.f, 0.f};
        bf16x8 cur[4], nxt[4];
#pragma unroll
        for (int kk = 0; kk < 4; ++kk) cur[kk] = *(const bf16x8*)(bp + kk * 32);
#pragma unroll
        for (int t = 0; t < 16; ++t) {
            if (t < 15) {
                const short* np = bp + (t + 1) * 16 * D;
#pragma unroll
                for (int kk = 0; kk < 4; ++kk) nxt[kk] = *(const bf16x8*)(np + kk * 32);
            }
            f32x4 acc = {0.f, 0.f, 0.f, 0.f};
#pragma unroll
            for (int kk = 0; kk < 4; ++kk)
                acc = __builtin_amdgcn_mfma_f32_16x16x32_bf16(afrag[kk], cur[kk], acc, 0, 0, 0);
            int c = wave * 256 + t * 16 + l15;
#pragma unroll
            for (int rg = 0; rg < 4; ++rg) {
                int rloc = quad * 4 + rg;
                float v = acc[rg];
                bool masked = (c == rowBase + rloc) || (c == pos_s[rloc]);
                v = masked ? -1e30f : v;
                int tb = tBin_s[rloc];
                int bin = st ? bin_of(v) : 0;
                if (bin > tb) {
                    partial[rg] += __expf(v * INV_TAU);
                } else if (bin == tb) {
                    int ix = atomicAdd(&cCnt[rloc], 1);
                    if (ix < CCAP) cand[rloc * BSTRIDE + ix] = v;
                }
            }
#pragma unroll
            for (int kk = 0; kk < 4; ++kk) cur[kk] = nxt[kk];
        }
        // reduce partials across the 16 lanes sharing each quad (cols)
#pragma unroll
        for (int rg = 0; rg < 4; ++rg) {
            float v = partial[rg];
            v += __shfl_xor(v, 1);
            v += __shfl_xor(v, 2);
            v += __shfl_xor(v, 4);
            v += __shfl_xor(v, 8);
            if (l15 == 0) atomicAdd(&rowSum[quad * 4 + rg], v);
        }
    }
    __syncthreads();

    // ---- exact rank-select among candidates: wave w -> row w ----
    {
        int rloc = wave;
        int m = min(cCnt[rloc], CCAP);
        int rem = tRem_s[rloc];
        for (int i = lane; i < m; i += 64) {
            float v = cand[rloc * BSTRIDE + i];
            int less = 0, eq = 0;
            for (int j = 0; j < m; ++j) {
                float w = cand[rloc * BSTRIDE + j];
                less += (w < v);
                eq += (w == v);
            }
            if (less <= rem && rem < less + eq) tVal_s[rloc] = v;
        }
    }
    __syncthreads();

    // ---- final: sum candidates >= t, add rowSum, write ----
    {
        int rloc = wave;
        int m = min(cCnt[rloc], CCAP);
        float tv = tVal_s[rloc];
        float csum = 0.0f;
        for (int i = lane; i < m; i += 64) {
            float v = cand[rloc * BSTRIDE + i];
            if (v >= tv) csum += __expf(v * INV_TAU);
        }
#pragma unroll
        for (int off = 1; off < 64; off <<= 1) csum += __shfl_xor(csum, off);
        if (lane == 0) s_out[rowBase + rloc] = rowSum[rloc] + csum;
    }
}

// ---------- K4: per-pair positive cos + two-level loss reduction ----------
__global__ __launch_bounds__(1024) void loss_kernel(const float* __restrict__ hpn,
                                                    const float* __restrict__ s,
                                                    const int* __restrict__ pp,
                                                    float* __restrict__ out, int K,
                                                    float scale) {
    int wave = threadIdx.x >> 6, lane = threadIdx.x & 63;
    int k = blockIdx.x * 16 + wave;
    float part = 0.0f;
    if (k < K) {
        int a = pp[2 * k], b = pp[2 * k + 1];
        float dsum = hpn[a * D + lane] * hpn[b * D + lane] +
                     hpn[a * D + lane + 64] * hpn[b * D + lane + 64];
#pragma unroll
        for (int off = 32; off > 0; off >>= 1) dsum += __shfl_down(dsum, off);
        if (lane == 0) {
            float p = __expf(dsum * INV_TAU);
            part = log1pf(s[a] / p) + log1pf(s[b] / p);
        }
    }
    __shared__ float red[16];
    if (lane == 0) red[wave] = part;
    __syncthreads();
    if (threadIdx.x == 0) {
        float tot = 0.0f;
#pragma unroll
        for (int w = 0; w < 16; ++w) tot += red[w];
        atomicAdd(out, tot * scale);
    }
}

extern "C" void kernel_launch(void* const* d_in, const int* in_sizes, int n_in,
                              void* d_out, int out_size, void* d_ws, size_t ws_size,
                              hipStream_t stream) {
    const float* emb = (const float*)d_in[0];
    const int* pp = (const int*)d_in[1];
    const int* stage = (const int*)d_in[2];
    int N = in_sizes[0] / D;  // 4096
    int K = in_sizes[1] / 2;  // 4096 pairs

    char* ws = (char*)d_ws;
    size_t offPos = 0;
    size_t offHnn = offPos + (size_t)N * 4;      // bf16 N*D
    size_t offHpn = offHnn + (size_t)N * D * 2;  // fp32 N*D
    size_t offS = offHpn + (size_t)N * D * 4;
    int* pos = (int*)(ws + offPos);
    __hip_bfloat16* hnn = (__hip_bfloat16*)(ws + offHnn);
    float* hpn = (float*)(ws + offHpn);
    float* s = (float*)(ws + offS);

    scatter_pos<<<(K + 255) / 256, 256, 0, stream>>>(pp, pos, (float*)d_out, K);
    prep_kernel<<<N + K, D, 0, stream>>>(emb, pos, pp, hnn, hpn, N);
    int q = (int)(0.8 * (double)(N - 1));  // 3276 for N=4096
    fused_gram_select<<<N / 16, 1024, 0, stream>>>(hnn, pos, stage, s, N, q);
    loss_kernel<<<(K + 15) / 16, 1024, 0, stream>>>(hpn, s, pp, (float*)d_out, K,
                                                    1.0f / (2.0f * K));
}

// Round 5
// 122.670 us; speedup vs baseline: 1.1637x; 1.1637x over previous
//
#include <hip/hip_runtime.h>
#include <hip/hip_bf16.h>
#include <math.h>

#define D 128
#define INV_TAU 5.0f

typedef short bf16x8 __attribute__((ext_vector_type(8)));
typedef unsigned short u16x8 __attribute__((ext_vector_type(8)));
typedef float f32x4 __attribute__((ext_vector_type(4)));

// ---------- K1: pos[a] = b for each pair; zero the output scalar ----------
__global__ void scatter_pos(const int* __restrict__ pp, int* __restrict__ pos,
                            float* __restrict__ out, int K) {
    int k = blockIdx.x * blockDim.x + threadIdx.x;
    if (k == 0) *out = 0.0f;
    if (k < K) pos[pp[2 * k]] = pp[2 * k + 1];
}

// ---------- K2: prep — blocks [0,N): partner (inline) + hard_neg norm -> bf16;
//                      blocks [N,N+K): hard_pos norm -> fp32 ----------
__global__ void prep_kernel(const float* __restrict__ emb, const int* __restrict__ pos,
                            const int* __restrict__ pp, unsigned short* __restrict__ hnn,
                            float* __restrict__ hpn, int N) {
    int b = blockIdx.x, d = threadIdx.x;  // blockDim = 128
    __shared__ int sP;
    __shared__ float tmp[2];
    bool isHn = (b < N);
    if (isHn && d == 0) {
        int r = b, posr = pos[r];
        int jmax = -1;
        for (int j = N - 1; j >= 0; --j) {
            if (j != r && j != posr) { jmax = j; break; }
        }
        int imax = -1;
        for (int i = N - 1; i >= 0; --i) {
            if (i != r && pos[i] != r) { imax = i; break; }
        }
        long long rowm = (jmax >= 0) ? (long long)r * N + jmax : -1;
        long long colm = (imax >= 0) ? (long long)imax * N + r : -1;
        sP = (colm > rowm) ? (imax < 0 ? 0 : imax) : (jmax < 0 ? 0 : jmax);
    }
    __syncthreads();
    float h;
    int outrow;
    if (isHn) {
        int p = sP;
        h = 0.5f * (emb[b * D + d] + emb[p * D + d]);
        outrow = b;
    } else {
        int k = b - N;
        int a = pp[2 * k], bb = pp[2 * k + 1];
        h = 1.5f * emb[a * D + d] - 0.5f * emb[bb * D + d];
        outrow = a;
    }
    float ss = h * h;
#pragma unroll
    for (int off = 32; off > 0; off >>= 1) ss += __shfl_down(ss, off);
    if ((d & 63) == 0) tmp[d >> 6] = ss;
    __syncthreads();
    float inv = 1.0f / fmaxf(sqrtf(tmp[0] + tmp[1]), 1e-8f);
    if (isHn) {
        __hip_bfloat16 hb = __float2bfloat16(h * inv);
        hnn[outrow * D + d] = *(unsigned short*)&hb;
    } else {
        hpn[outrow * D + d] = h * inv;
    }
}

// ---------- K3: 128x128-tile bf16 MFMA GEMM -> bf16 sims (masked = 0xFF7F) ----------
// 256 thr = 4 waves; wave (rowhalf, colhalf) computes a 64x64 quadrant.
// LDS row stride 136 shorts (272 B): frag ds_read_b128 is 2-way-conflict-free.
__global__ __launch_bounds__(256) void gemm_sim(const unsigned short* __restrict__ hnn,
                                                const int* __restrict__ pos,
                                                unsigned short* __restrict__ sims, int N) {
    __shared__ unsigned short As[128 * 136];
    __shared__ unsigned short Bs[128 * 136];
    __shared__ int pos_s[128];
    int tid = threadIdx.x;
    int rowBase = blockIdx.y * 128, colBase = blockIdx.x * 128;
    if (tid < 128) pos_s[tid] = pos[rowBase + tid];

    u16x8 ra[8], rb[8];
#pragma unroll
    for (int i = 0; i < 8; ++i) {
        int idx = i * 256 + tid;
        int row = idx >> 4, seg = idx & 15;
        ra[i] = *(const u16x8*)&hnn[(size_t)(rowBase + row) * D + seg * 8];
        rb[i] = *(const u16x8*)&hnn[(size_t)(colBase + row) * D + seg * 8];
    }
#pragma unroll
    for (int i = 0; i < 8; ++i) {
        int idx = i * 256 + tid;
        int row = idx >> 4, seg = idx & 15;
        *(u16x8*)&As[row * 136 + seg * 8] = ra[i];
        *(u16x8*)&Bs[row * 136 + seg * 8] = rb[i];
    }
    __syncthreads();

    int wave = tid >> 6, lane = tid & 63;
    int quad = lane >> 4, l15 = lane & 15;
    int rowhalf = wave >> 1, colhalf = wave & 1;

    f32x4 acc[4][4] = {};
#pragma unroll
    for (int kk = 0; kk < 4; ++kk) {
        bf16x8 af[4], bf[4];
#pragma unroll
        for (int rt = 0; rt < 4; ++rt)
            af[rt] = *(const bf16x8*)&As[(rowhalf * 64 + rt * 16 + l15) * 136 + kk * 32 + quad * 8];
#pragma unroll
        for (int ct = 0; ct < 4; ++ct)
            bf[ct] = *(const bf16x8*)&Bs[(colhalf * 64 + ct * 16 + l15) * 136 + kk * 32 + quad * 8];
#pragma unroll
        for (int rt = 0; rt < 4; ++rt)
#pragma unroll
            for (int ct = 0; ct < 4; ++ct)
                acc[rt][ct] = __builtin_amdgcn_mfma_f32_16x16x32_bf16(af[rt], bf[ct],
                                                                     acc[rt][ct], 0, 0, 0);
    }

#pragma unroll
    for (int rt = 0; rt < 4; ++rt) {
#pragma unroll
        for (int rg = 0; rg < 4; ++rg) {
            int rloc = rowhalf * 64 + rt * 16 + quad * 4 + rg;
            int r = rowBase + rloc;
            int pr = pos_s[rloc];
#pragma unroll
            for (int ct = 0; ct < 4; ++ct) {
                int c = colBase + colhalf * 64 + ct * 16 + l15;
                float v = acc[rt][ct][rg];
                __hip_bfloat16 hb = __float2bfloat16(v);
                unsigned short u = *(unsigned short*)&hb;
                if (c == r || c == pr) u = 0xFF7F;  // -3.39e38 -> exp() == 0
                sims[(size_t)r * N + c] = u;
            }
        }
    }
}

// ---------- K4: wave-per-row exact rank-select + exp-sum (register-resident) ----------
// 512 thr = 8 waves = 8 rows per block. Row values -> sortable u16 in 64 regs/lane.
// Exact rank q via 16-step bitwise binary search (cmp + wave-reduce, no LDS).
__global__ __launch_bounds__(512) void select_kernel(const unsigned short* __restrict__ sims,
                                                     const int* __restrict__ stage,
                                                     float* __restrict__ s_out, int N, int q) {
    int wave = threadIdx.x >> 6, lane = threadIdx.x & 63;
    int row = blockIdx.x * 8 + wave;
    const unsigned short* rp = sims + (size_t)row * N;

    unsigned s[64];
#pragma unroll
    for (int j = 0; j < 8; ++j) {
        u16x8 t = *(const u16x8*)&rp[j * 512 + lane * 8];
#pragma unroll
        for (int e = 0; e < 8; ++e) {
            unsigned u = (unsigned)(unsigned short)t[e];
            // map bf16 bits -> sortable u16: sign? ~u : u|0x8000
            s[j * 8 + e] = (u & 0x8000u) ? (~u & 0xFFFFu) : (u | 0x8000u);
        }
    }

    unsigned T = 0;
    if (stage[0]) {
#pragma unroll
        for (int b = 15; b >= 0; --b) {
            unsigned cand = T | (1u << b);
            int cnt = 0;
#pragma unroll
            for (int i = 0; i < 64; ++i) cnt += (s[i] < cand);
#pragma unroll
            for (int off = 1; off < 64; off <<= 1) cnt += __shfl_xor(cnt, off);
            if (cnt <= q) T = cand;  // rank-q element is >= cand
        }
    }

    float sum = 0.0f;
#pragma unroll
    for (int i = 0; i < 64; ++i) {
        if (s[i] >= T) {
            unsigned u = (s[i] & 0x8000u) ? (s[i] ^ 0x8000u) : (~s[i] & 0xFFFFu);
            float f = __uint_as_float(u << 16);
            sum += __expf(f * INV_TAU);
        }
    }
#pragma unroll
    for (int off = 1; off < 64; off <<= 1) sum += __shfl_xor(sum, off);
    if (lane == 0) s_out[row] = sum;
}

// ---------- K5: per-pair positive cos + two-level loss reduction ----------
__global__ __launch_bounds__(1024) void loss_kernel(const float* __restrict__ hpn,
                                                    const float* __restrict__ s,
                                                    const int* __restrict__ pp,
                                                    float* __restrict__ out, int K,
                                                    float scale) {
    int wave = threadIdx.x >> 6, lane = threadIdx.x & 63;
    int k = blockIdx.x * 16 + wave;
    float part = 0.0f;
    if (k < K) {
        int a = pp[2 * k], b = pp[2 * k + 1];
        float dsum = hpn[a * D + lane] * hpn[b * D + lane] +
                     hpn[a * D + lane + 64] * hpn[b * D + lane + 64];
#pragma unroll
        for (int off = 32; off > 0; off >>= 1) dsum += __shfl_down(dsum, off);
        if (lane == 0) {
            float p = __expf(dsum * INV_TAU);
            part = log1pf(s[a] / p) + log1pf(s[b] / p);
        }
    }
    __shared__ float red[16];
    if (lane == 0) red[wave] = part;
    __syncthreads();
    if (threadIdx.x == 0) {
        float tot = 0.0f;
#pragma unroll
        for (int w = 0; w < 16; ++w) tot += red[w];
        atomicAdd(out, tot * scale);
    }
}

extern "C" void kernel_launch(void* const* d_in, const int* in_sizes, int n_in,
                              void* d_out, int out_size, void* d_ws, size_t ws_size,
                              hipStream_t stream) {
    const float* emb = (const float*)d_in[0];
    const int* pp = (const int*)d_in[1];
    const int* stage = (const int*)d_in[2];
    int N = in_sizes[0] / D;  // 4096
    int K = in_sizes[1] / 2;  // 4096 pairs

    char* ws = (char*)d_ws;
    size_t offPos = 0;
    size_t offHnn = offPos + (size_t)N * 4;       // u16 N*D
    size_t offHpn = offHnn + (size_t)N * D * 2;   // fp32 N*D
    size_t offS = offHpn + (size_t)N * D * 4;     // fp32 N
    size_t offSims = offS + (size_t)N * 4;        // u16 N*N (32 MB)
    int* pos = (int*)(ws + offPos);
    unsigned short* hnn = (unsigned short*)(ws + offHnn);
    float* hpn = (float*)(ws + offHpn);
    float* s = (float*)(ws + offS);
    unsigned short* sims = (unsigned short*)(ws + offSims);

    scatter_pos<<<(K + 255) / 256, 256, 0, stream>>>(pp, pos, (float*)d_out, K);
    prep_kernel<<<N + K, D, 0, stream>>>(emb, pos, pp, hnn, hpn, N);
    dim3 g(N / 128, N / 128);
    gemm_sim<<<g, 256, 0, stream>>>(hnn, pos, sims, N);
    int q = (int)(0.8 * (double)(N - 1));  // 3276 for N=4096
    select_kernel<<<N / 8, 512, 0, stream>>>(sims, stage, s, N, q);
    loss_kernel<<<(K + 15) / 16, 1024, 0, stream>>>(hpn, s, pp, (float*)d_out, K,
                                                    1.0f / (2.0f * K));
}